// Round 15
// baseline (92.495 us; speedup 1.0000x reference)
//
#include <hip/hip_runtime.h>
#include <math.h>

// ---------------------------------------------------------------------------
// CAM module, fused MFMA version (hi/lo-bf16 q/k/energy path).
//   k_prep:        [Wq;Wk] -> tiled hi/lo bf16 (32-k rows)
//   k_conv_energy: 256x128 tile, 8 waves, grid (32,8). Conv uses
//                  mfma_32x32x16 (fewer/cheaper MFMAs); B staged as one col x
//                  8k per thread -> b128 LDS writes. Energy = 4 K-chunks of
//                  [256][32], 16x16 MFMA (proven layout).
//   k_softmax_M:   reduce 32 partials, softmax(rowmin-e), M=A@Wv, ob=A@bv
//   k_out:         out = M @ X + ob   (plain bf16 MFMA, HBM-bound)
// Numerics: bf16-RTN q/k FAILS (R4) — hi/lo split required.
// R5: const-indexed reg arrays. R6: no __shared__ ptr arrays. R9: lgkm-only
// raw barrier. R12: throughput-bound. R13: native cvt. R14: halved traffic.
// R15: 32x32x16 conv MFMA (194 vs 233 cyc/step) + b128 staging writes.
// ---------------------------------------------------------------------------

typedef float f32x4  __attribute__((ext_vector_type(4)));
typedef float f32x16 __attribute__((ext_vector_type(16)));
typedef short s16x8  __attribute__((ext_vector_type(8)));

__device__ __forceinline__ unsigned short f2bf(float f) {
  union { __bf16 b; unsigned short u; } v;
  v.b = (__bf16)f;            // HW RNE convert; pairs fuse to v_cvt_pk_bf16_f32
  return v.u;
}
__device__ __forceinline__ float bf2f(unsigned short h) {
  union { unsigned u; float f; } v; v.u = ((unsigned)h) << 16;
  return v.f;
}
__device__ __forceinline__ unsigned pack2(unsigned short a, unsigned short b) {
  return (unsigned)a | ((unsigned)b << 16);
}
__device__ __forceinline__ void cvt_hilo(float a, float b,
                                         unsigned& hw, unsigned& lw) {
  unsigned short ha = f2bf(a), hb = f2bf(b);
  hw = pack2(ha, hb);
  lw = pack2(f2bf(a - bf2f(ha)), f2bf(b - bf2f(hb)));
}

// ---------------- Kernel 0: W -> tiled hi/lo bf16 --------------------------
__global__ __launch_bounds__(256) void k_prep(
    const float* __restrict__ Wq, const float* __restrict__ Wk,
    unsigned short* __restrict__ Wth, unsigned short* __restrict__ Wtl) {
  const int f = (blockIdx.x * 256 + threadIdx.x) * 4;
  const int row = f >> 9;
  const int k   = f & 511;
  const float* src = (row < 128) ? &Wq[row * 512 + k] : &Wk[(row - 128) * 512 + k];
  float4 v = *(const float4*)src;
  unsigned short h0 = f2bf(v.x), h1 = f2bf(v.y), h2 = f2bf(v.z), h3 = f2bf(v.w);
  unsigned short l0 = f2bf(v.x - bf2f(h0)), l1 = f2bf(v.y - bf2f(h1));
  unsigned short l2 = f2bf(v.z - bf2f(h2)), l3 = f2bf(v.w - bf2f(h3));
  const int di = (k >> 5) * 8192 + row * 32 + (k & 31);
  *(ushort4*)&Wth[di] = make_ushort4(h0, h1, h2, h3);
  *(ushort4*)&Wtl[di] = make_ushort4(l0, l1, l2, l3);
}

// ---------------- Kernel 1: fused conv + energy partial --------------------
// grid (32 nt, 8 b), 512 thr = 8 waves (4 row-groups x 2 col-groups).
// Conv: wave (wr,wc) owns rows wr*64..+63, cols wc*64..+63, as 2x2 of 32x32.
__global__ __launch_bounds__(512) void k_conv_energy(
    const float* __restrict__ x,
    const unsigned short* __restrict__ Wth, const unsigned short* __restrict__ Wtl,
    const float* __restrict__ bq, const float* __restrict__ bk,
    float* __restrict__ epart) {
  __shared__ unsigned short LDS[20480];   // 40 KiB
  // conv: buf c at u16 offset c*10240 (Bh), +5120 (Bl). energy: Th@0, Tl@8192.
  unsigned short* Th = LDS;
  unsigned short* Tl = LDS + 8192;

  const int t = threadIdx.x;
  const int nt = blockIdx.x, b = blockIdx.y;
  const int w = t >> 6, lane = t & 63;
  const int wr = w >> 1, wc = w & 1;
  const int l31 = lane & 31, l5 = lane >> 5;

  // B staging map: thread owns col_s (0..127) x k-segment kseg*8..+7.
  const int col_s = t & 127;
  const int kseg  = t >> 7;          // 0..3
  const int ci0   = 2 * kseg;        // ci pair {ci0, ci0+1}
  const int ohl   = col_s >> 6;
  const int ow    = col_s & 63;
  const float* xb = x + ((size_t)b << 21);
  const float* xs = xb + (size_t)ci0 * 16384 + (nt * 4 + ohl * 2) * 128 + 2 * ow;
  const int sidx = col_s * 40 + kseg * 8;   // u16 index of this thread's b128 slot

  f32x16 acc[2][2];
#pragma unroll
  for (int tm = 0; tm < 2; ++tm)
#pragma unroll
    for (int tn = 0; tn < 2; ++tn)
#pragma unroll
      for (int r = 0; r < 16; ++r) acc[tm][tn][r] = 0.f;

  float2 pv[2][4];              // x pingpong: [buf][cio*2+kh]
  const int aoff0 = (wr * 64 + l31) * 32 + l5 * 8;   // +tm*1024 +h*16
  const int boff0 = (wc * 64 + l31) * 40 + l5 * 8;   // +tn*1280 +h*16

  // -------- prologue: x(0) -> buf0 ; x(1) -> pv[1] -------------------------
  {
    float2 p0 = *(const float2*)&xs[0];
    float2 p1 = *(const float2*)&xs[128];
    float2 p2 = *(const float2*)&xs[16384];
    float2 p3 = *(const float2*)&xs[16384 + 128];
    uint4 hi, lo;
    cvt_hilo(p0.x, p0.y, hi.x, lo.x);
    cvt_hilo(p1.x, p1.y, hi.y, lo.y);
    cvt_hilo(p2.x, p2.y, hi.z, lo.z);
    cvt_hilo(p3.x, p3.y, hi.w, lo.w);
    *(uint4*)&LDS[sidx]        = hi;
    *(uint4*)&LDS[5120 + sidx] = lo;
  }
  pv[1][0] = *(const float2*)&xs[(size_t)8 * 16384];
  pv[1][1] = *(const float2*)&xs[(size_t)8 * 16384 + 128];
  pv[1][2] = *(const float2*)&xs[(size_t)8 * 16384 + 16384];
  pv[1][3] = *(const float2*)&xs[(size_t)8 * 16384 + 16384 + 128];
  __syncthreads();

  // -------- main loop: 1 lgkm-only barrier/step ----------------------------
#pragma unroll
  for (int step = 0; step < 16; ++step) {
    const int cur = step & 1;
    const unsigned short* Bh = LDS + cur * 10240;
    const unsigned short* Bl = Bh + 5120;
    s16x8 bh[2][2], bl[2][2];
#pragma unroll
    for (int tn = 0; tn < 2; ++tn)
#pragma unroll
      for (int h = 0; h < 2; ++h) {
        const int bidx = boff0 + tn * 1280 + h * 16;
        bh[tn][h] = *(const s16x8*)&Bh[bidx];
        bl[tn][h] = *(const s16x8*)&Bl[bidx];
      }
    const unsigned short* Wh_s = Wth + step * 8192;
    const unsigned short* Wl_s = Wtl + step * 8192;
    s16x8 ah[2][2], al[2][2];
#pragma unroll
    for (int tm = 0; tm < 2; ++tm)
#pragma unroll
      for (int h = 0; h < 2; ++h) {
        const int aidx = aoff0 + tm * 1024 + h * 16;
        ah[tm][h] = *(const s16x8*)&Wh_s[aidx];
        al[tm][h] = *(const s16x8*)&Wl_s[aidx];
      }
    // x(s+2)
    if (step < 14) {
      const float* xn = xs + (size_t)(step + 2) * 8 * 16384;
      pv[cur][0] = *(const float2*)&xn[0];
      pv[cur][1] = *(const float2*)&xn[128];
      pv[cur][2] = *(const float2*)&xn[16384];
      pv[cur][3] = *(const float2*)&xn[16384 + 128];
    }
    // MFMA (32x32x16, hi/lo split: 3 products)
#pragma unroll
    for (int h = 0; h < 2; ++h)
#pragma unroll
      for (int tm = 0; tm < 2; ++tm)
#pragma unroll
        for (int tn = 0; tn < 2; ++tn) {
          acc[tm][tn] = __builtin_amdgcn_mfma_f32_32x32x16_bf16(ah[tm][h], bh[tn][h], acc[tm][tn], 0, 0, 0);
          acc[tm][tn] = __builtin_amdgcn_mfma_f32_32x32x16_bf16(ah[tm][h], bl[tn][h], acc[tm][tn], 0, 0, 0);
          acc[tm][tn] = __builtin_amdgcn_mfma_f32_32x32x16_bf16(al[tm][h], bh[tn][h], acc[tm][tn], 0, 0, 0);
        }
    // stage x(s+1) -> buf[cur^1]
    if (step < 15) {
      unsigned short* Nh = LDS + (cur ^ 1) * 10240;
      unsigned short* Nl = Nh + 5120;
      uint4 hi, lo;
      cvt_hilo(pv[cur ^ 1][0].x, pv[cur ^ 1][0].y, hi.x, lo.x);
      cvt_hilo(pv[cur ^ 1][1].x, pv[cur ^ 1][1].y, hi.y, lo.y);
      cvt_hilo(pv[cur ^ 1][2].x, pv[cur ^ 1][2].y, hi.z, lo.z);
      cvt_hilo(pv[cur ^ 1][3].x, pv[cur ^ 1][3].y, hi.w, lo.w);
      *(uint4*)&Nh[sidx] = hi;
      *(uint4*)&Nl[sidx] = lo;
      asm volatile("s_waitcnt lgkmcnt(0)" ::: "memory");
      __builtin_amdgcn_s_barrier();
    }
  }
  __syncthreads();   // full drain before LDS repurpose

  // ---- phase 2+3: energy in four 32-col K-chunks ([256][32] tile) ---------
  // bias groups: row = rbase + tm*32 + (r&3) + 8*(r>>2) + 4*l5
  const float* biasp = (wr < 2) ? bq : bk;
  const int rbase = (wr & 1) * 64;
  float4 bg[2][4];
#pragma unroll
  for (int tm = 0; tm < 2; ++tm)
#pragma unroll
    for (int g = 0; g < 4; ++g)
      bg[tm][g] = *(const float4*)&biasp[rbase + tm * 32 + g * 8 + 4 * l5];

  f32x4 e[2][4];
#pragma unroll
  for (int mm = 0; mm < 2; ++mm)
#pragma unroll
    for (int nf = 0; nf < 4; ++nf) e[mm][nf] = (f32x4){0.f, 0.f, 0.f, 0.f};

  const int lrow = lane & 15, lkb = lane >> 4;
  const int qg = w >> 1;                 // q-row group (32 rows)
  const int kg = w & 1;                  // k-col group (64 cols)

#pragma unroll
  for (int ks = 0; ks < 4; ++ks) {
    // repack acc cols [32ks,+32) + bias -> hi/lo chunk tile, XOR-swizzled.
    if (wc == (ks >> 1)) {
      const int tn = ks & 1;
#pragma unroll
      for (int tm = 0; tm < 2; ++tm)
#pragma unroll
        for (int r = 0; r < 16; ++r) {
          const int row = wr * 64 + tm * 32 + (r & 3) + 8 * (r >> 2) + 4 * l5;
          const float vv = acc[tm][tn][r] + ((const float*)&bg[tm][r >> 2])[r & 3];
          const unsigned short h = f2bf(vv);
          const unsigned short l = f2bf(vv - bf2f(h));
          const int ad = row * 32 + (((l31 >> 3) ^ (row & 3)) << 3) + (l31 & 7);
          Th[ad] = h;
          Tl[ad] = l;
        }
    }
    __syncthreads();
    // fragments + MFMA for this 32-wide K-slice (16x16, proven layout)
    {
      s16x8 qh[2], ql[2], kh8[4], kl8[4];
#pragma unroll
      for (int mm = 0; mm < 2; ++mm) {
        const int r = qg * 32 + mm * 16 + lrow;
        const int ad = r * 32 + ((lkb ^ (r & 3)) << 3);
        qh[mm] = *(const s16x8*)&Th[ad];
        ql[mm] = *(const s16x8*)&Tl[ad];
      }
#pragma unroll
      for (int nf = 0; nf < 4; ++nf) {
        const int r = 128 + kg * 64 + nf * 16 + lrow;
        const int ad = r * 32 + ((lkb ^ (r & 3)) << 3);
        kh8[nf] = *(const s16x8*)&Th[ad];
        kl8[nf] = *(const s16x8*)&Tl[ad];
      }
#pragma unroll
      for (int mm = 0; mm < 2; ++mm)
#pragma unroll
        for (int nf = 0; nf < 4; ++nf) {
          e[mm][nf] = __builtin_amdgcn_mfma_f32_16x16x32_bf16(qh[mm], kh8[nf], e[mm][nf], 0, 0, 0);
          e[mm][nf] = __builtin_amdgcn_mfma_f32_16x16x32_bf16(qh[mm], kl8[nf], e[mm][nf], 0, 0, 0);
          e[mm][nf] = __builtin_amdgcn_mfma_f32_16x16x32_bf16(ql[mm], kh8[nf], e[mm][nf], 0, 0, 0);
        }
    }
    if (ks < 3) __syncthreads();
  }

  float* ep = epart + ((size_t)b * 32 + nt) * 16384;
#pragma unroll
  for (int mm = 0; mm < 2; ++mm) {
    const int qr0 = qg * 32 + mm * 16 + (lane >> 4) * 4;
#pragma unroll
    for (int nf = 0; nf < 4; ++nf) {
      const int kc = kg * 64 + nf * 16 + (lane & 15);
#pragma unroll
      for (int i = 0; i < 4; ++i)
        ep[(size_t)(qr0 + i) * 128 + kc] = e[mm][nf][i];
    }
  }
}

// ---------------- Kernel 2: reduce + softmax + M = A@Wv, ob = A@bv ---------
__global__ __launch_bounds__(256) void k_softmax_M(
    const float* __restrict__ epart, const float* __restrict__ Wv,
    const float* __restrict__ bv, float* __restrict__ Mbuf,
    float* __restrict__ outbb) {
  __shared__ float As[4][128];
  const int t = threadIdx.x;
  const int wid = t >> 6, lane = t & 63;
  const int b = blockIdx.x >> 5;
  const int c = (blockIdx.x & 31) * 4 + wid;
  const int d0 = lane * 2;

  float2 s = make_float2(0.f, 0.f);
#pragma unroll 4
  for (int p = 0; p < 32; ++p) {
    float2 e = *(const float2*)&epart[((size_t)b * 32 + p) * 16384 + c * 128 + d0];
    s.x += e.x; s.y += e.y;
  }
  float mn = fminf(s.x, s.y);
#pragma unroll
  for (int off = 1; off < 64; off <<= 1) mn = fminf(mn, __shfl_xor(mn, off));
  const float p0 = expf(mn - s.x);
  const float p1 = expf(mn - s.y);
  float tot = p0 + p1;
#pragma unroll
  for (int off = 1; off < 64; off <<= 1) tot += __shfl_xor(tot, off);
  const float inv = 1.f / tot;
  const float a0 = p0 * inv, a1 = p1 * inv;

  const float2 bvv = *(const float2*)&bv[d0];
  float ob = a0 * bvv.x + a1 * bvv.y;
#pragma unroll
  for (int off = 1; off < 64; off <<= 1) ob += __shfl_xor(ob, off);
  if (lane == 0) outbb[b * 128 + c] = ob;

  As[wid][d0] = a0;
  As[wid][d0 + 1] = a1;   // wave-local write->read, lockstep-safe
  float m0 = 0.f, m1 = 0.f;
#pragma unroll 4
  for (int d = 0; d < 128; ++d) {
    const float a = As[wid][d];
    const float2 wv = *(const float2*)&Wv[d * 128 + d0];
    m0 = fmaf(a, wv.x, m0);
    m1 = fmaf(a, wv.y, m1);
  }
  *(float2*)&Mbuf[(size_t)b * 16384 + c * 128 + d0] = make_float2(m0, m1);
}

// ---------------- Kernel 3: out = M @ X + ob, plain bf16 MFMA --------------
__global__ __launch_bounds__(256) void k_out(
    const float* __restrict__ x, const float* __restrict__ Mbuf,
    const float* __restrict__ outbb, float* __restrict__ out) {
  __shared__ unsigned short Ms[128 * 40];
  __shared__ unsigned short Xs[128 * 40];
  const int t = threadIdx.x;
  const int nt = blockIdx.x, b = blockIdx.y;
  const int wid = t >> 6, lane = t & 63;
  const int wr = wid >> 1, wc = wid & 1;
  const int lrow = lane & 15, lkb = lane >> 4;
  const int am = t >> 1, ak0 = (t & 1) * 16;
  const int xkl = (t >> 5) * 4;
  const int xc0 = (t & 31) * 4;

  const float* xb = x + ((size_t)b << 21);
  const float* Mb = Mbuf + (size_t)b * 16384;
  float* ob = out + ((size_t)b << 21);

  f32x4 acc[4][4];
#pragma unroll
  for (int m = 0; m < 4; ++m)
#pragma unroll
    for (int n = 0; n < 4; ++n) acc[m][n] = (f32x4){0.f, 0.f, 0.f, 0.f};

  for (int step = 0; step < 4; ++step) {
    const int kk = step * 32;
    {
      float w[16];
      *(float4*)&w[0]  = *(const float4*)&Mb[am * 128 + kk + ak0];
      *(float4*)&w[4]  = *(const float4*)&Mb[am * 128 + kk + ak0 + 4];
      *(float4*)&w[8]  = *(const float4*)&Mb[am * 128 + kk + ak0 + 8];
      *(float4*)&w[12] = *(const float4*)&Mb[am * 128 + kk + ak0 + 12];
      unsigned short hs[16];
#pragma unroll
      for (int i = 0; i < 16; ++i) hs[i] = f2bf(w[i]);
      *(uint4*)&Ms[am * 40 + ak0]     = *(uint4*)&hs[0];
      *(uint4*)&Ms[am * 40 + ak0 + 8] = *(uint4*)&hs[8];
    }
#pragma unroll
    for (int q = 0; q < 4; ++q) {
      const int kl = xkl + q;
      float4 v = *(const float4*)&xb[(size_t)(kk + kl) * 16384 + nt * 128 + xc0];
      Xs[(xc0 + 0) * 40 + kl] = f2bf(v.x);
      Xs[(xc0 + 1) * 40 + kl] = f2bf(v.y);
      Xs[(xc0 + 2) * 40 + kl] = f2bf(v.z);
      Xs[(xc0 + 3) * 40 + kl] = f2bf(v.w);
    }
    __syncthreads();
    s16x8 af[4], bf[4];
#pragma unroll
    for (int m = 0; m < 4; ++m)
      af[m] = *(const s16x8*)&Ms[(wr * 64 + m * 16 + lrow) * 40 + lkb * 8];
#pragma unroll
    for (int n = 0; n < 4; ++n)
      bf[n] = *(const s16x8*)&Xs[(wc * 64 + n * 16 + lrow) * 40 + lkb * 8];
#pragma unroll
    for (int m = 0; m < 4; ++m)
#pragma unroll
      for (int n = 0; n < 4; ++n)
        acc[m][n] = __builtin_amdgcn_mfma_f32_16x16x32_bf16(af[m], bf[n], acc[m][n], 0, 0, 0);
    __syncthreads();
  }
#pragma unroll
  for (int m = 0; m < 4; ++m) {
    const int r0 = wr * 64 + m * 16 + (lane >> 4) * 4;
#pragma unroll
    for (int n = 0; n < 4; ++n) {
      const int gc = nt * 128 + wc * 64 + n * 16 + (lane & 15);
#pragma unroll
      for (int i = 0; i < 4; ++i) {
        const int row = r0 + i;
        ob[(size_t)row * 16384 + gc] = acc[m][n][i] + outbb[b * 128 + row];
      }
    }
  }
}

// ---------------------------------------------------------------------------
extern "C" void kernel_launch(void* const* d_in, const int* in_sizes, int n_in,
                              void* d_out, int out_size, void* d_ws, size_t ws_size,
                              hipStream_t stream) {
  const float* x  = (const float*)d_in[0];
  const float* Wq = (const float*)d_in[1];
  const float* bq = (const float*)d_in[2];
  const float* Wk = (const float*)d_in[3];
  const float* bk = (const float*)d_in[4];
  const float* Wv = (const float*)d_in[5];
  const float* bv = (const float*)d_in[6];
  float* out = (float*)d_out;
  char* ws = (char*)d_ws;

  float* epart = (float*)ws;                               // 16 MiB
  float* Mbuf  = (float*)(ws + 16777216);                  // 512 KiB
  float* outbb = (float*)(ws + 17301504);                  // 4 KiB
  unsigned short* Wth = (unsigned short*)(ws + 17305600);  // 256 KiB
  unsigned short* Wtl = (unsigned short*)(ws + 17567744);  // 256 KiB

  hipLaunchKernelGGL(k_prep, dim3(128), dim3(256), 0, stream, Wq, Wk, Wth, Wtl);
  hipLaunchKernelGGL(k_conv_energy, dim3(32, 8), dim3(512), 0, stream,
                     x, Wth, Wtl, bq, bk, epart);
  hipLaunchKernelGGL(k_softmax_M, dim3(256), dim3(256), 0, stream,
                     epart, Wv, bv, Mbuf, outbb);
  hipLaunchKernelGGL(k_out, dim3(128, 8), dim3(256), 0, stream,
                     x, Mbuf, outbb, out);
}

// Round 16
// 84.585 us; speedup vs baseline: 1.0935x; 1.0935x over previous
//
#include <hip/hip_runtime.h>
#include <math.h>

// ---------------------------------------------------------------------------
// CAM module — best-of assembly (R16).
//   conv+energy: R13's proven config (64-col tile, 4 waves, 32KB LDS,
//                16x16 MFMA hi/lo split, chunked energy) — ~36us measured.
//   softmax_M:   256-block wave-per-row (full GPU), 64 partials.
//   k_out:       R13 verbatim (~HBM floor).
// Numerics: bf16-RTN q/k FAILS (R4) — hi/lo split required.
// R15 lesson: 32x32 MFMA regressed — 4 accumulators x 3-deep hi/lo chains
// kill ILP; 16x16's 16 independent accumulators win despite more issues.
// ---------------------------------------------------------------------------

typedef float f32x4 __attribute__((ext_vector_type(4)));
typedef short s16x8 __attribute__((ext_vector_type(8)));

__device__ __forceinline__ unsigned short f2bf(float f) {
  union { __bf16 b; unsigned short u; } v;
  v.b = (__bf16)f;            // HW RNE convert; pairs fuse to v_cvt_pk_bf16_f32
  return v.u;
}
__device__ __forceinline__ float bf2f(unsigned short h) {
  union { unsigned u; float f; } v; v.u = ((unsigned)h) << 16;
  return v.f;
}
__device__ __forceinline__ unsigned pack2(unsigned short a, unsigned short b) {
  return (unsigned)a | ((unsigned)b << 16);
}

// ---------------- Kernel 0: W -> tiled hi/lo bf16 --------------------------
__global__ __launch_bounds__(256) void k_prep(
    const float* __restrict__ Wq, const float* __restrict__ Wk,
    unsigned short* __restrict__ Wth, unsigned short* __restrict__ Wtl) {
  const int f = (blockIdx.x * 256 + threadIdx.x) * 4;
  const int row = f >> 9;
  const int k   = f & 511;
  const float* src = (row < 128) ? &Wq[row * 512 + k] : &Wk[(row - 128) * 512 + k];
  float4 v = *(const float4*)src;
  unsigned short h0 = f2bf(v.x), h1 = f2bf(v.y), h2 = f2bf(v.z), h3 = f2bf(v.w);
  unsigned short l0 = f2bf(v.x - bf2f(h0)), l1 = f2bf(v.y - bf2f(h1));
  unsigned short l2 = f2bf(v.z - bf2f(h2)), l3 = f2bf(v.w - bf2f(h3));
  const int di = (k >> 5) * 8192 + row * 32 + (k & 31);
  *(ushort4*)&Wth[di] = make_ushort4(h0, h1, h2, h3);
  *(ushort4*)&Wtl[di] = make_ushort4(l0, l1, l2, l3);
}

// ---------------- Kernel 1: fused conv + energy partial (R13 verbatim) -----
// grid (64 nt, 8 b), 256 thr = 4 waves. Rows 0-255 (q:0-127,k:128-255),
// cols nt*64..+63, K=512 in 16 fully-unrolled steps of 32 (split-bf16).
// LDS 32 KB: conv B dbuf {0,2560},{5120,7680}; energy chunk tile [256][32].
__global__ __launch_bounds__(256, 3) void k_conv_energy(
    const float* __restrict__ x,
    const unsigned short* __restrict__ Wth, const unsigned short* __restrict__ Wtl,
    const float* __restrict__ bq, const float* __restrict__ bk,
    float* __restrict__ epart) {
  __shared__ unsigned short LDS[16384];   // 32 KiB, unioned across phases
  unsigned short* Th = LDS;               // energy chunk hi (256*32 u16)
  unsigned short* Tl = LDS + 8192;        // energy chunk lo

  const int t = threadIdx.x;
  const int nt = blockIdx.x, b = blockIdx.y;
  const int w = t >> 6, lane = t & 63;
  const int lrow = lane & 15, lkb = lane >> 4;

  // B staging map: pp=(ci_l,kh); thread i16 stages output cols i16+16g.
  const int pp = t >> 4;
  const int ci_l = pp >> 1, kh = pp & 1;
  const int i16 = t & 15;
  const int klb = ci_l * 4 + kh * 2;
  const float* xb = x + ((size_t)b << 21);
  const float* xrow = xb + (size_t)ci_l * 16384 + (2 * nt + kh) * 128 + 2 * i16;

  f32x4 acc[4][4];
#pragma unroll
  for (int m = 0; m < 4; ++m)
#pragma unroll
    for (int n = 0; n < 4; ++n) acc[m][n] = (f32x4){0.f, 0.f, 0.f, 0.f};

  // pipelined register state (constant-indexed under full unroll)
  s16x8 pfh[4], pfl[4];         // A fragments for current step (depth-1)
  float2 pv[2][4];              // x pingpong: pv[(s+1)&1] = x(s+1)
  const int aoff = (w * 64 + lrow) * 32 + lkb * 8;

  // -------- prologue --------------------------------------------------------
#pragma unroll
  for (int m = 0; m < 4; ++m) {           // A(0)
    pfh[m] = *(const s16x8*)&Wth[aoff + m * 512];
    pfl[m] = *(const s16x8*)&Wtl[aoff + m * 512];
  }
  {                                        // x(0) -> stage buf0 directly
    float2 v0 = *(const float2*)&xrow[0];
    float2 v1 = *(const float2*)&xrow[32];
    float2 v2 = *(const float2*)&xrow[64];
    float2 v3 = *(const float2*)&xrow[96];
    unsigned short hx, hy;
    hx = f2bf(v0.x); hy = f2bf(v0.y);
    *(unsigned*)&LDS[(i16     ) * 40 + klb] = pack2(hx, hy);
    *(unsigned*)&LDS[2560 + (i16     ) * 40 + klb] = pack2(f2bf(v0.x - bf2f(hx)), f2bf(v0.y - bf2f(hy)));
    hx = f2bf(v1.x); hy = f2bf(v1.y);
    *(unsigned*)&LDS[(i16 + 16) * 40 + klb] = pack2(hx, hy);
    *(unsigned*)&LDS[2560 + (i16 + 16) * 40 + klb] = pack2(f2bf(v1.x - bf2f(hx)), f2bf(v1.y - bf2f(hy)));
    hx = f2bf(v2.x); hy = f2bf(v2.y);
    *(unsigned*)&LDS[(i16 + 32) * 40 + klb] = pack2(hx, hy);
    *(unsigned*)&LDS[2560 + (i16 + 32) * 40 + klb] = pack2(f2bf(v2.x - bf2f(hx)), f2bf(v2.y - bf2f(hy)));
    hx = f2bf(v3.x); hy = f2bf(v3.y);
    *(unsigned*)&LDS[(i16 + 48) * 40 + klb] = pack2(hx, hy);
    *(unsigned*)&LDS[2560 + (i16 + 48) * 40 + klb] = pack2(f2bf(v3.x - bf2f(hx)), f2bf(v3.y - bf2f(hy)));
  }
#pragma unroll
  for (int g = 0; g < 4; ++g)              // x(1) -> pv[1]
    pv[1][g] = *(const float2*)&xrow[(size_t)8 * 16384 + 32 * g];
  __syncthreads();

  // -------- main loop: 1 lgkm-only barrier/step ----------------------------
#pragma unroll
  for (int step = 0; step < 16; ++step) {
    const int cur = step & 1;
    // B fragments for THIS step from buf[cur]
    const unsigned short* Bh = LDS + cur * 5120;
    const unsigned short* Bl = Bh + 2560;
    s16x8 bfh[4], bfl[4];
#pragma unroll
    for (int nf = 0; nf < 4; ++nf) {
      const int bidx = (nf * 16 + lrow) * 40 + lkb * 8;
      bfh[nf] = *(const s16x8*)&Bh[bidx];
      bfl[nf] = *(const s16x8*)&Bl[bidx];
    }
    // MFMA on A(s) [pf] x B(s)
#pragma unroll
    for (int m = 0; m < 4; ++m)
#pragma unroll
      for (int n = 0; n < 4; ++n) {
        acc[m][n] = __builtin_amdgcn_mfma_f32_16x16x32_bf16(pfh[m], bfh[n], acc[m][n], 0, 0, 0);
        acc[m][n] = __builtin_amdgcn_mfma_f32_16x16x32_bf16(pfh[m], bfl[n], acc[m][n], 0, 0, 0);
        acc[m][n] = __builtin_amdgcn_mfma_f32_16x16x32_bf16(pfl[m], bfh[n], acc[m][n], 0, 0, 0);
      }
    // A(s+1) (issued first so its wait leaves x loads in flight)
    if (step < 15) {
      const unsigned short* Wh_n = Wth + (step + 1) * 8192;
      const unsigned short* Wl_n = Wtl + (step + 1) * 8192;
#pragma unroll
      for (int m = 0; m < 4; ++m) {
        pfh[m] = *(const s16x8*)&Wh_n[aoff + m * 512];
        pfl[m] = *(const s16x8*)&Wl_n[aoff + m * 512];
      }
    }
    // x(s+2) (youngest loads; never force-drained)
    if (step < 14) {
#pragma unroll
      for (int g = 0; g < 4; ++g)
        pv[cur][g] = *(const float2*)&xrow[(size_t)(step + 2) * 8 * 16384 + 32 * g];
    }
    // stage x(s+1) = pv[cur^1] -> buf[cur^1]
    if (step < 15) {
      unsigned short* Nh = LDS + (cur ^ 1) * 5120;
      unsigned short* Nl = Nh + 2560;
#pragma unroll
      for (int g = 0; g < 4; ++g) {
        const int n = i16 + 16 * g;
        unsigned short hx = f2bf(pv[cur ^ 1][g].x), hy = f2bf(pv[cur ^ 1][g].y);
        *(unsigned*)&Nh[n * 40 + klb] = pack2(hx, hy);
        *(unsigned*)&Nl[n * 40 + klb] = pack2(f2bf(pv[cur ^ 1][g].x - bf2f(hx)),
                                              f2bf(pv[cur ^ 1][g].y - bf2f(hy)));
      }
      // raw barrier: drain LDS only — globals stay in flight
      asm volatile("s_waitcnt lgkmcnt(0)" ::: "memory");
      __builtin_amdgcn_s_barrier();
    }
  }
  __syncthreads();   // full drain before LDS repurpose

  // ---- phase 2+3: energy in two 32-col K-chunks (32 KB tile) --------------
  const float* biasp = (w < 2) ? bq : bk;
  const int rb = (w & 1) * 64;
  float biasr[16];
#pragma unroll
  for (int m = 0; m < 4; ++m)
#pragma unroll
    for (int i = 0; i < 4; ++i)
      biasr[m * 4 + i] = biasp[rb + m * 16 + (lane >> 4) * 4 + i];

  f32x4 e[4][4];
#pragma unroll
  for (int m = 0; m < 4; ++m)
#pragma unroll
    for (int n = 0; n < 4; ++n) e[m][n] = (f32x4){0.f, 0.f, 0.f, 0.f};

  const int mrow0 = (w >> 1) * 64;       // q-half rows (0 or 64)
  const int nrow0 = 128 + (w & 1) * 64;  // k-half rows

#pragma unroll
  for (int ks = 0; ks < 2; ++ks) {
    // repack acc cols [32ks, 32ks+32) + bias -> hi/lo chunk tile, swizzled
#pragma unroll
    for (int m = 0; m < 4; ++m) {
      const int r0 = w * 64 + m * 16 + (lane >> 4) * 4;
#pragma unroll
      for (int nn = 0; nn < 2; ++nn) {
        const int n = 2 * ks + nn;
        const int cl = nn * 16 + lrow;       // local col 0..31
        const int cl8 = cl >> 3, c7 = cl & 7;
#pragma unroll
        for (int i = 0; i < 4; ++i) {
          const int r = r0 + i;
          const float vv = acc[m][n][i] + biasr[m * 4 + i];
          const unsigned short h = f2bf(vv);
          const unsigned short l = f2bf(vv - bf2f(h));
          const int ad = r * 32 + ((cl8 ^ (r & 3)) << 3) + c7;
          Th[ad] = h;
          Tl[ad] = l;
        }
      }
    }
    __syncthreads();
    // fragments + MFMA for this 32-wide K-slice
    {
      s16x8 qh[4], ql[4], kh8[4], kl8[4];
#pragma unroll
      for (int m = 0; m < 4; ++m) {
        const int r = mrow0 + m * 16 + lrow;
        const int ad = r * 32 + ((lkb ^ (r & 3)) << 3);
        qh[m] = *(const s16x8*)&Th[ad];
        ql[m] = *(const s16x8*)&Tl[ad];
      }
#pragma unroll
      for (int n = 0; n < 4; ++n) {
        const int r = nrow0 + n * 16 + lrow;
        const int ad = r * 32 + ((lkb ^ (r & 3)) << 3);
        kh8[n] = *(const s16x8*)&Th[ad];
        kl8[n] = *(const s16x8*)&Tl[ad];
      }
#pragma unroll
      for (int m = 0; m < 4; ++m)
#pragma unroll
        for (int n = 0; n < 4; ++n) {
          e[m][n] = __builtin_amdgcn_mfma_f32_16x16x32_bf16(qh[m], kh8[n], e[m][n], 0, 0, 0);
          e[m][n] = __builtin_amdgcn_mfma_f32_16x16x32_bf16(qh[m], kl8[n], e[m][n], 0, 0, 0);
          e[m][n] = __builtin_amdgcn_mfma_f32_16x16x32_bf16(ql[m], kh8[n], e[m][n], 0, 0, 0);
        }
    }
    if (ks == 0) __syncthreads();   // protect chunk-1 repack
  }

  float* ep = epart + ((size_t)b * 64 + nt) * 16384;
#pragma unroll
  for (int m = 0; m < 4; ++m) {
    const int qr = (w >> 1) * 64 + m * 16 + (lane >> 4) * 4;
#pragma unroll
    for (int n = 0; n < 4; ++n) {
      const int kr = (w & 1) * 64 + n * 16 + lrow;
#pragma unroll
      for (int i = 0; i < 4; ++i) ep[(size_t)(qr + i) * 128 + kr] = e[m][n][i];
    }
  }
}

// ---------------- Kernel 2: reduce + softmax + M = A@Wv, ob = A@bv ---------
// grid (256): b = blk>>5, c = (blk&31)*4 + wid; wave per row, float2 lanes.
__global__ __launch_bounds__(256) void k_softmax_M(
    const float* __restrict__ epart, const float* __restrict__ Wv,
    const float* __restrict__ bv, float* __restrict__ Mbuf,
    float* __restrict__ outbb) {
  __shared__ float As[4][128];
  const int t = threadIdx.x;
  const int wid = t >> 6, lane = t & 63;
  const int b = blockIdx.x >> 5;
  const int c = (blockIdx.x & 31) * 4 + wid;
  const int d0 = lane * 2;

  float2 s = make_float2(0.f, 0.f);
#pragma unroll 4
  for (int p = 0; p < 64; ++p) {
    float2 e = *(const float2*)&epart[((size_t)b * 64 + p) * 16384 + c * 128 + d0];
    s.x += e.x; s.y += e.y;
  }
  float mn = fminf(s.x, s.y);
#pragma unroll
  for (int off = 1; off < 64; off <<= 1) mn = fminf(mn, __shfl_xor(mn, off));
  const float p0 = expf(mn - s.x);
  const float p1 = expf(mn - s.y);
  float tot = p0 + p1;
#pragma unroll
  for (int off = 1; off < 64; off <<= 1) tot += __shfl_xor(tot, off);
  const float inv = 1.f / tot;
  const float a0 = p0 * inv, a1 = p1 * inv;

  const float2 bvv = *(const float2*)&bv[d0];
  float ob = a0 * bvv.x + a1 * bvv.y;
#pragma unroll
  for (int off = 1; off < 64; off <<= 1) ob += __shfl_xor(ob, off);
  if (lane == 0) outbb[b * 128 + c] = ob;

  As[wid][d0] = a0;
  As[wid][d0 + 1] = a1;   // wave-local write->read, lockstep-safe
  float m0 = 0.f, m1 = 0.f;
#pragma unroll 4
  for (int d = 0; d < 128; ++d) {
    const float a = As[wid][d];
    const float2 wv = *(const float2*)&Wv[d * 128 + d0];
    m0 = fmaf(a, wv.x, m0);
    m1 = fmaf(a, wv.y, m1);
  }
  *(float2*)&Mbuf[(size_t)b * 16384 + c * 128 + d0] = make_float2(m0, m1);
}

// ---------------- Kernel 3: out = M @ X + ob, plain bf16 MFMA --------------
__global__ __launch_bounds__(256) void k_out(
    const float* __restrict__ x, const float* __restrict__ Mbuf,
    const float* __restrict__ outbb, float* __restrict__ out) {
  __shared__ unsigned short Ms[128 * 40];
  __shared__ unsigned short Xs[128 * 40];
  const int t = threadIdx.x;
  const int nt = blockIdx.x, b = blockIdx.y;
  const int wid = t >> 6, lane = t & 63;
  const int wr = wid >> 1, wc = wid & 1;
  const int lrow = lane & 15, lkb = lane >> 4;
  const int am = t >> 1, ak0 = (t & 1) * 16;
  const int xkl = (t >> 5) * 4;
  const int xc0 = (t & 31) * 4;

  const float* xb = x + ((size_t)b << 21);
  const float* Mb = Mbuf + (size_t)b * 16384;
  float* ob = out + ((size_t)b << 21);

  f32x4 acc[4][4];
#pragma unroll
  for (int m = 0; m < 4; ++m)
#pragma unroll
    for (int n = 0; n < 4; ++n) acc[m][n] = (f32x4){0.f, 0.f, 0.f, 0.f};

  for (int step = 0; step < 4; ++step) {
    const int kk = step * 32;
    {
      float w[16];
      *(float4*)&w[0]  = *(const float4*)&Mb[am * 128 + kk + ak0];
      *(float4*)&w[4]  = *(const float4*)&Mb[am * 128 + kk + ak0 + 4];
      *(float4*)&w[8]  = *(const float4*)&Mb[am * 128 + kk + ak0 + 8];
      *(float4*)&w[12] = *(const float4*)&Mb[am * 128 + kk + ak0 + 12];
      unsigned short hs[16];
#pragma unroll
      for (int i = 0; i < 16; ++i) hs[i] = f2bf(w[i]);
      *(uint4*)&Ms[am * 40 + ak0]     = *(uint4*)&hs[0];
      *(uint4*)&Ms[am * 40 + ak0 + 8] = *(uint4*)&hs[8];
    }
#pragma unroll
    for (int q = 0; q < 4; ++q) {
      const int kl = xkl + q;
      float4 v = *(const float4*)&xb[(size_t)(kk + kl) * 16384 + nt * 128 + xc0];
      Xs[(xc0 + 0) * 40 + kl] = f2bf(v.x);
      Xs[(xc0 + 1) * 40 + kl] = f2bf(v.y);
      Xs[(xc0 + 2) * 40 + kl] = f2bf(v.z);
      Xs[(xc0 + 3) * 40 + kl] = f2bf(v.w);
    }
    __syncthreads();
    s16x8 af[4], bf[4];
#pragma unroll
    for (int m = 0; m < 4; ++m)
      af[m] = *(const s16x8*)&Ms[(wr * 64 + m * 16 + lrow) * 40 + lkb * 8];
#pragma unroll
    for (int n = 0; n < 4; ++n)
      bf[n] = *(const s16x8*)&Xs[(wc * 64 + n * 16 + lrow) * 40 + lkb * 8];
#pragma unroll
    for (int m = 0; m < 4; ++m)
#pragma unroll
      for (int n = 0; n < 4; ++n)
        acc[m][n] = __builtin_amdgcn_mfma_f32_16x16x32_bf16(af[m], bf[n], acc[m][n], 0, 0, 0);
    __syncthreads();
  }
#pragma unroll
  for (int m = 0; m < 4; ++m) {
    const int r0 = wr * 64 + m * 16 + (lane >> 4) * 4;
#pragma unroll
    for (int n = 0; n < 4; ++n) {
      const int gc = nt * 128 + wc * 64 + n * 16 + (lane & 15);
#pragma unroll
      for (int i = 0; i < 4; ++i) {
        const int row = r0 + i;
        ob[(size_t)row * 16384 + gc] = acc[m][n][i] + outbb[b * 128 + row];
      }
    }
  }
}

// ---------------------------------------------------------------------------
extern "C" void kernel_launch(void* const* d_in, const int* in_sizes, int n_in,
                              void* d_out, int out_size, void* d_ws, size_t ws_size,
                              hipStream_t stream) {
  const float* x  = (const float*)d_in[0];
  const float* Wq = (const float*)d_in[1];
  const float* bq = (const float*)d_in[2];
  const float* Wk = (const float*)d_in[3];
  const float* bk = (const float*)d_in[4];
  const float* Wv = (const float*)d_in[5];
  const float* bv = (const float*)d_in[6];
  float* out = (float*)d_out;
  char* ws = (char*)d_ws;

  float* epart = (float*)ws;                               // 64*16384*4*8 = 32 MiB
  float* Mbuf  = (float*)(ws + 33554432);                  // 512 KiB
  float* outbb = (float*)(ws + 34078720);                  // 4 KiB
  unsigned short* Wth = (unsigned short*)(ws + 34082816);  // 256 KiB
  unsigned short* Wtl = (unsigned short*)(ws + 34344960);  // 256 KiB

  hipLaunchKernelGGL(k_prep, dim3(128), dim3(256), 0, stream, Wq, Wk, Wth, Wtl);
  hipLaunchKernelGGL(k_conv_energy, dim3(64, 8), dim3(256), 0, stream,
                     x, Wth, Wtl, bq, bk, epart);
  hipLaunchKernelGGL(k_softmax_M, dim3(256), dim3(256), 0, stream,
                     epart, Wv, bv, Mbuf, outbb);
  hipLaunchKernelGGL(k_out, dim3(128, 8), dim3(256), 0, stream,
                     x, Mbuf, outbb, out);
}

// Round 17
// 80.978 us; speedup vs baseline: 1.1422x; 1.0445x over previous
//
#include <hip/hip_runtime.h>
#include <math.h>

// ---------------------------------------------------------------------------
// CAM module — R17: R16 conv + streamlined k_out.
//   k_prep:        [Wq;Wk] -> tiled hi/lo bf16, fragment-coalesced layout
//   k_conv_energy: R13/R16 proven config (64-col tile, 4 waves, 32KB LDS).
//   k_softmax_M:   reduce 64 partials, softmax(rowmin-e), M=A@Wv written as
//                  bf16 in MFMA-tiled layout Mt[step][row][32], ob=A@bv.
//   k_out:         out = Mt @ X + ob. A-frags global->VGPR (L2), X dbuf LDS
//                  with lgkm-only raw barrier (1/step). Bit-identical output.
// Numerics: bf16-RTN q/k FAILS (R4) — hi/lo split required on q/k/energy.
// R15: 32x32 MFMA kills ILP (4 acc x 3-deep chains) — stay 16x16.
// R12: throughput-bound; R13: native cvt; R9: lgkm-only barrier.
// ---------------------------------------------------------------------------

typedef float f32x4 __attribute__((ext_vector_type(4)));
typedef short s16x8 __attribute__((ext_vector_type(8)));

__device__ __forceinline__ unsigned short f2bf(float f) {
  union { __bf16 b; unsigned short u; } v;
  v.b = (__bf16)f;            // HW RNE convert; pairs fuse to v_cvt_pk_bf16_f32
  return v.u;
}
__device__ __forceinline__ float bf2f(unsigned short h) {
  union { unsigned u; float f; } v; v.u = ((unsigned)h) << 16;
  return v.f;
}
__device__ __forceinline__ unsigned pack2(unsigned short a, unsigned short b) {
  return (unsigned)a | ((unsigned)b << 16);
}

// ---------------- Kernel 0: W -> tiled hi/lo bf16 --------------------------
__global__ __launch_bounds__(256) void k_prep(
    const float* __restrict__ Wq, const float* __restrict__ Wk,
    unsigned short* __restrict__ Wth, unsigned short* __restrict__ Wtl) {
  const int f = (blockIdx.x * 256 + threadIdx.x) * 4;
  const int row = f >> 9;
  const int k   = f & 511;
  const float* src = (row < 128) ? &Wq[row * 512 + k] : &Wk[(row - 128) * 512 + k];
  float4 v = *(const float4*)src;
  unsigned short h0 = f2bf(v.x), h1 = f2bf(v.y), h2 = f2bf(v.z), h3 = f2bf(v.w);
  unsigned short l0 = f2bf(v.x - bf2f(h0)), l1 = f2bf(v.y - bf2f(h1));
  unsigned short l2 = f2bf(v.z - bf2f(h2)), l3 = f2bf(v.w - bf2f(h3));
  const int di = (k >> 5) * 8192 + row * 32 + (k & 31);
  *(ushort4*)&Wth[di] = make_ushort4(h0, h1, h2, h3);
  *(ushort4*)&Wtl[di] = make_ushort4(l0, l1, l2, l3);
}

// ---------------- Kernel 1: fused conv + energy partial (R16 verbatim) -----
__global__ __launch_bounds__(256, 3) void k_conv_energy(
    const float* __restrict__ x,
    const unsigned short* __restrict__ Wth, const unsigned short* __restrict__ Wtl,
    const float* __restrict__ bq, const float* __restrict__ bk,
    float* __restrict__ epart) {
  __shared__ unsigned short LDS[16384];   // 32 KiB, unioned across phases
  unsigned short* Th = LDS;               // energy chunk hi (256*32 u16)
  unsigned short* Tl = LDS + 8192;        // energy chunk lo

  const int t = threadIdx.x;
  const int nt = blockIdx.x, b = blockIdx.y;
  const int w = t >> 6, lane = t & 63;
  const int lrow = lane & 15, lkb = lane >> 4;

  const int pp = t >> 4;
  const int ci_l = pp >> 1, kh = pp & 1;
  const int i16 = t & 15;
  const int klb = ci_l * 4 + kh * 2;
  const float* xb = x + ((size_t)b << 21);
  const float* xrow = xb + (size_t)ci_l * 16384 + (2 * nt + kh) * 128 + 2 * i16;

  f32x4 acc[4][4];
#pragma unroll
  for (int m = 0; m < 4; ++m)
#pragma unroll
    for (int n = 0; n < 4; ++n) acc[m][n] = (f32x4){0.f, 0.f, 0.f, 0.f};

  s16x8 pfh[4], pfl[4];
  float2 pv[2][4];
  const int aoff = (w * 64 + lrow) * 32 + lkb * 8;

#pragma unroll
  for (int m = 0; m < 4; ++m) {
    pfh[m] = *(const s16x8*)&Wth[aoff + m * 512];
    pfl[m] = *(const s16x8*)&Wtl[aoff + m * 512];
  }
  {
    float2 v0 = *(const float2*)&xrow[0];
    float2 v1 = *(const float2*)&xrow[32];
    float2 v2 = *(const float2*)&xrow[64];
    float2 v3 = *(const float2*)&xrow[96];
    unsigned short hx, hy;
    hx = f2bf(v0.x); hy = f2bf(v0.y);
    *(unsigned*)&LDS[(i16     ) * 40 + klb] = pack2(hx, hy);
    *(unsigned*)&LDS[2560 + (i16     ) * 40 + klb] = pack2(f2bf(v0.x - bf2f(hx)), f2bf(v0.y - bf2f(hy)));
    hx = f2bf(v1.x); hy = f2bf(v1.y);
    *(unsigned*)&LDS[(i16 + 16) * 40 + klb] = pack2(hx, hy);
    *(unsigned*)&LDS[2560 + (i16 + 16) * 40 + klb] = pack2(f2bf(v1.x - bf2f(hx)), f2bf(v1.y - bf2f(hy)));
    hx = f2bf(v2.x); hy = f2bf(v2.y);
    *(unsigned*)&LDS[(i16 + 32) * 40 + klb] = pack2(hx, hy);
    *(unsigned*)&LDS[2560 + (i16 + 32) * 40 + klb] = pack2(f2bf(v2.x - bf2f(hx)), f2bf(v2.y - bf2f(hy)));
    hx = f2bf(v3.x); hy = f2bf(v3.y);
    *(unsigned*)&LDS[(i16 + 48) * 40 + klb] = pack2(hx, hy);
    *(unsigned*)&LDS[2560 + (i16 + 48) * 40 + klb] = pack2(f2bf(v3.x - bf2f(hx)), f2bf(v3.y - bf2f(hy)));
  }
#pragma unroll
  for (int g = 0; g < 4; ++g)
    pv[1][g] = *(const float2*)&xrow[(size_t)8 * 16384 + 32 * g];
  __syncthreads();

#pragma unroll
  for (int step = 0; step < 16; ++step) {
    const int cur = step & 1;
    const unsigned short* Bh = LDS + cur * 5120;
    const unsigned short* Bl = Bh + 2560;
    s16x8 bfh[4], bfl[4];
#pragma unroll
    for (int nf = 0; nf < 4; ++nf) {
      const int bidx = (nf * 16 + lrow) * 40 + lkb * 8;
      bfh[nf] = *(const s16x8*)&Bh[bidx];
      bfl[nf] = *(const s16x8*)&Bl[bidx];
    }
#pragma unroll
    for (int m = 0; m < 4; ++m)
#pragma unroll
      for (int n = 0; n < 4; ++n) {
        acc[m][n] = __builtin_amdgcn_mfma_f32_16x16x32_bf16(pfh[m], bfh[n], acc[m][n], 0, 0, 0);
        acc[m][n] = __builtin_amdgcn_mfma_f32_16x16x32_bf16(pfh[m], bfl[n], acc[m][n], 0, 0, 0);
        acc[m][n] = __builtin_amdgcn_mfma_f32_16x16x32_bf16(pfl[m], bfh[n], acc[m][n], 0, 0, 0);
      }
    if (step < 15) {
      const unsigned short* Wh_n = Wth + (step + 1) * 8192;
      const unsigned short* Wl_n = Wtl + (step + 1) * 8192;
#pragma unroll
      for (int m = 0; m < 4; ++m) {
        pfh[m] = *(const s16x8*)&Wh_n[aoff + m * 512];
        pfl[m] = *(const s16x8*)&Wl_n[aoff + m * 512];
      }
    }
    if (step < 14) {
#pragma unroll
      for (int g = 0; g < 4; ++g)
        pv[cur][g] = *(const float2*)&xrow[(size_t)(step + 2) * 8 * 16384 + 32 * g];
    }
    if (step < 15) {
      unsigned short* Nh = LDS + (cur ^ 1) * 5120;
      unsigned short* Nl = Nh + 2560;
#pragma unroll
      for (int g = 0; g < 4; ++g) {
        const int n = i16 + 16 * g;
        unsigned short hx = f2bf(pv[cur ^ 1][g].x), hy = f2bf(pv[cur ^ 1][g].y);
        *(unsigned*)&Nh[n * 40 + klb] = pack2(hx, hy);
        *(unsigned*)&Nl[n * 40 + klb] = pack2(f2bf(pv[cur ^ 1][g].x - bf2f(hx)),
                                              f2bf(pv[cur ^ 1][g].y - bf2f(hy)));
      }
      asm volatile("s_waitcnt lgkmcnt(0)" ::: "memory");
      __builtin_amdgcn_s_barrier();
    }
  }
  __syncthreads();

  const float* biasp = (w < 2) ? bq : bk;
  const int rb = (w & 1) * 64;
  float biasr[16];
#pragma unroll
  for (int m = 0; m < 4; ++m)
#pragma unroll
    for (int i = 0; i < 4; ++i)
      biasr[m * 4 + i] = biasp[rb + m * 16 + (lane >> 4) * 4 + i];

  f32x4 e[4][4];
#pragma unroll
  for (int m = 0; m < 4; ++m)
#pragma unroll
    for (int n = 0; n < 4; ++n) e[m][n] = (f32x4){0.f, 0.f, 0.f, 0.f};

  const int mrow0 = (w >> 1) * 64;
  const int nrow0 = 128 + (w & 1) * 64;

#pragma unroll
  for (int ks = 0; ks < 2; ++ks) {
#pragma unroll
    for (int m = 0; m < 4; ++m) {
      const int r0 = w * 64 + m * 16 + (lane >> 4) * 4;
#pragma unroll
      for (int nn = 0; nn < 2; ++nn) {
        const int n = 2 * ks + nn;
        const int cl = nn * 16 + lrow;
        const int cl8 = cl >> 3, c7 = cl & 7;
#pragma unroll
        for (int i = 0; i < 4; ++i) {
          const int r = r0 + i;
          const float vv = acc[m][n][i] + biasr[m * 4 + i];
          const unsigned short h = f2bf(vv);
          const unsigned short l = f2bf(vv - bf2f(h));
          const int ad = r * 32 + ((cl8 ^ (r & 3)) << 3) + c7;
          Th[ad] = h;
          Tl[ad] = l;
        }
      }
    }
    __syncthreads();
    {
      s16x8 qh[4], ql[4], kh8[4], kl8[4];
#pragma unroll
      for (int m = 0; m < 4; ++m) {
        const int r = mrow0 + m * 16 + lrow;
        const int ad = r * 32 + ((lkb ^ (r & 3)) << 3);
        qh[m] = *(const s16x8*)&Th[ad];
        ql[m] = *(const s16x8*)&Tl[ad];
      }
#pragma unroll
      for (int n = 0; n < 4; ++n) {
        const int r = nrow0 + n * 16 + lrow;
        const int ad = r * 32 + ((lkb ^ (r & 3)) << 3);
        kh8[n] = *(const s16x8*)&Th[ad];
        kl8[n] = *(const s16x8*)&Tl[ad];
      }
#pragma unroll
      for (int m = 0; m < 4; ++m)
#pragma unroll
        for (int n = 0; n < 4; ++n) {
          e[m][n] = __builtin_amdgcn_mfma_f32_16x16x32_bf16(qh[m], kh8[n], e[m][n], 0, 0, 0);
          e[m][n] = __builtin_amdgcn_mfma_f32_16x16x32_bf16(qh[m], kl8[n], e[m][n], 0, 0, 0);
          e[m][n] = __builtin_amdgcn_mfma_f32_16x16x32_bf16(ql[m], kh8[n], e[m][n], 0, 0, 0);
        }
    }
    if (ks == 0) __syncthreads();
  }

  float* ep = epart + ((size_t)b * 64 + nt) * 16384;
#pragma unroll
  for (int m = 0; m < 4; ++m) {
    const int qr = (w >> 1) * 64 + m * 16 + (lane >> 4) * 4;
#pragma unroll
    for (int n = 0; n < 4; ++n) {
      const int kr = (w & 1) * 64 + n * 16 + lrow;
#pragma unroll
      for (int i = 0; i < 4; ++i) ep[(size_t)(qr + i) * 128 + kr] = e[m][n][i];
    }
  }
}

// ---------------- Kernel 2: reduce + softmax + Mt(bf16 tiled) + ob ---------
// grid (256): b = blk>>5, c = (blk&31)*4 + wid; wave per row, float2 lanes.
// Mt layout (per batch): [step=k/32][row][k&31] u16 — same as W tiling.
__global__ __launch_bounds__(256) void k_softmax_M(
    const float* __restrict__ epart, const float* __restrict__ Wv,
    const float* __restrict__ bv, unsigned short* __restrict__ Mt,
    float* __restrict__ outbb) {
  __shared__ float As[4][128];
  const int t = threadIdx.x;
  const int wid = t >> 6, lane = t & 63;
  const int b = blockIdx.x >> 5;
  const int c = (blockIdx.x & 31) * 4 + wid;
  const int d0 = lane * 2;

  float2 s = make_float2(0.f, 0.f);
#pragma unroll 4
  for (int p = 0; p < 64; ++p) {
    float2 e = *(const float2*)&epart[((size_t)b * 64 + p) * 16384 + c * 128 + d0];
    s.x += e.x; s.y += e.y;
  }
  float mn = fminf(s.x, s.y);
#pragma unroll
  for (int off = 1; off < 64; off <<= 1) mn = fminf(mn, __shfl_xor(mn, off));
  const float p0 = expf(mn - s.x);
  const float p1 = expf(mn - s.y);
  float tot = p0 + p1;
#pragma unroll
  for (int off = 1; off < 64; off <<= 1) tot += __shfl_xor(tot, off);
  const float inv = 1.f / tot;
  const float a0 = p0 * inv, a1 = p1 * inv;

  const float2 bvv = *(const float2*)&bv[d0];
  float ob = a0 * bvv.x + a1 * bvv.y;
#pragma unroll
  for (int off = 1; off < 64; off <<= 1) ob += __shfl_xor(ob, off);
  if (lane == 0) outbb[b * 128 + c] = ob;

  As[wid][d0] = a0;
  As[wid][d0 + 1] = a1;   // wave-local write->read, lockstep-safe
  float m0 = 0.f, m1 = 0.f;
#pragma unroll 4
  for (int d = 0; d < 128; ++d) {
    const float a = As[wid][d];
    const float2 wv = *(const float2*)&Wv[d * 128 + d0];
    m0 = fmaf(a, wv.x, m0);
    m1 = fmaf(a, wv.y, m1);
  }
  // write bf16 (single RNE round — identical to previous k_out conversion)
  const int sk = lane >> 4;            // d0>>5
  const int ko = (lane * 2) & 31;      // d0&31
  *(unsigned*)&Mt[(size_t)b * 16384 + sk * 4096 + c * 32 + ko] =
      pack2(f2bf(m0), f2bf(m1));
}

// ---------------- Kernel 3: out = Mt @ X + ob ------------------------------
// grid (128 nt, 8 b), 256 thr = 4 waves (2x2 of 64x64). K=128 in 4 steps.
// A-frags: direct global from Mt (L2-resident). X: LDS dbuf, lgkm barrier.
__global__ __launch_bounds__(256) void k_out(
    const float* __restrict__ x, const unsigned short* __restrict__ Mt,
    const float* __restrict__ outbb, float* __restrict__ out) {
  __shared__ unsigned short Xs[10240];   // 2 bufs x (128 cols x 40) u16
  const int t = threadIdx.x;
  const int nt = blockIdx.x, b = blockIdx.y;
  const int wid = t >> 6, lane = t & 63;
  const int wr = wid >> 1, wc = wid & 1;
  const int lrow = lane & 15, lkb = lane >> 4;
  const int xkl = (t >> 5) * 4;
  const int xc0 = (t & 31) * 4;

  const float* xb = x + ((size_t)b << 21);
  const unsigned short* Mb = Mt + (size_t)b * 16384;
  float* ob = out + ((size_t)b << 21);

  f32x4 acc[4][4];
#pragma unroll
  for (int m = 0; m < 4; ++m)
#pragma unroll
    for (int n = 0; n < 4; ++n) acc[m][n] = (f32x4){0.f, 0.f, 0.f, 0.f};

  float4 pv[2][4];
  // prologue: x(0) -> stage buf0 ; x(1) -> pv[1]
#pragma unroll
  for (int q = 0; q < 4; ++q) {
    float4 v = *(const float4*)&xb[(size_t)(xkl + q) * 16384 + nt * 128 + xc0];
    Xs[(xc0 + 0) * 40 + xkl + q] = f2bf(v.x);
    Xs[(xc0 + 1) * 40 + xkl + q] = f2bf(v.y);
    Xs[(xc0 + 2) * 40 + xkl + q] = f2bf(v.z);
    Xs[(xc0 + 3) * 40 + xkl + q] = f2bf(v.w);
  }
#pragma unroll
  for (int q = 0; q < 4; ++q)
    pv[1][q] = *(const float4*)&xb[(size_t)(32 + xkl + q) * 16384 + nt * 128 + xc0];
  __syncthreads();

#pragma unroll
  for (int step = 0; step < 4; ++step) {
    const int cur = step & 1;
    const unsigned short* Bx = Xs + cur * 5120;
    s16x8 bf[4];
#pragma unroll
    for (int n = 0; n < 4; ++n)
      bf[n] = *(const s16x8*)&Bx[(wc * 64 + n * 16 + lrow) * 40 + lkb * 8];
    s16x8 af[4];
#pragma unroll
    for (int m = 0; m < 4; ++m)
      af[m] = *(const s16x8*)&Mb[step * 4096 + (wr * 64 + m * 16 + lrow) * 32 + lkb * 8];
    // x(step+2)
    if (step < 2) {
#pragma unroll
      for (int q = 0; q < 4; ++q)
        pv[cur][q] = *(const float4*)&xb[(size_t)((step + 2) * 32 + xkl + q) * 16384 + nt * 128 + xc0];
    }
#pragma unroll
    for (int m = 0; m < 4; ++m)
#pragma unroll
      for (int n = 0; n < 4; ++n)
        acc[m][n] = __builtin_amdgcn_mfma_f32_16x16x32_bf16(af[m], bf[n], acc[m][n], 0, 0, 0);
    // stage x(step+1) -> buf[cur^1]
    if (step < 3) {
      unsigned short* Nx = Xs + (cur ^ 1) * 5120;
#pragma unroll
      for (int q = 0; q < 4; ++q) {
        Nx[(xc0 + 0) * 40 + xkl + q] = f2bf(pv[cur ^ 1][q].x);
        Nx[(xc0 + 1) * 40 + xkl + q] = f2bf(pv[cur ^ 1][q].y);
        Nx[(xc0 + 2) * 40 + xkl + q] = f2bf(pv[cur ^ 1][q].z);
        Nx[(xc0 + 3) * 40 + xkl + q] = f2bf(pv[cur ^ 1][q].w);
      }
      asm volatile("s_waitcnt lgkmcnt(0)" ::: "memory");
      __builtin_amdgcn_s_barrier();
    }
  }
#pragma unroll
  for (int m = 0; m < 4; ++m) {
    const int r0 = wr * 64 + m * 16 + (lane >> 4) * 4;
#pragma unroll
    for (int n = 0; n < 4; ++n) {
      const int gc = nt * 128 + wc * 64 + n * 16 + (lane & 15);
#pragma unroll
      for (int i = 0; i < 4; ++i) {
        const int row = r0 + i;
        ob[(size_t)row * 16384 + gc] = acc[m][n][i] + outbb[b * 128 + row];
      }
    }
  }
}

// ---------------------------------------------------------------------------
extern "C" void kernel_launch(void* const* d_in, const int* in_sizes, int n_in,
                              void* d_out, int out_size, void* d_ws, size_t ws_size,
                              hipStream_t stream) {
  const float* x  = (const float*)d_in[0];
  const float* Wq = (const float*)d_in[1];
  const float* bq = (const float*)d_in[2];
  const float* Wk = (const float*)d_in[3];
  const float* bk = (const float*)d_in[4];
  const float* Wv = (const float*)d_in[5];
  const float* bv = (const float*)d_in[6];
  float* out = (float*)d_out;
  char* ws = (char*)d_ws;

  float* epart = (float*)ws;                               // 32 MiB
  unsigned short* Mt = (unsigned short*)(ws + 33554432);   // 256 KiB (bf16)
  float* outbb = (float*)(ws + 33816576);                  // 4 KiB
  unsigned short* Wth = (unsigned short*)(ws + 33820672);  // 256 KiB
  unsigned short* Wtl = (unsigned short*)(ws + 34082816);  // 256 KiB

  hipLaunchKernelGGL(k_prep, dim3(128), dim3(256), 0, stream, Wq, Wk, Wth, Wtl);
  hipLaunchKernelGGL(k_conv_energy, dim3(64, 8), dim3(256), 0, stream,
                     x, Wth, Wtl, bq, bk, epart);
  hipLaunchKernelGGL(k_softmax_M, dim3(256), dim3(256), 0, stream,
                     epart, Wv, bv, Mt, outbb);
  hipLaunchKernelGGL(k_out, dim3(128, 8), dim3(256), 0, stream,
                     x, Mt, outbb, out);
}